// Round 6
// baseline (18494.463 us; speedup 1.0000x reference)
//
#include <hip/hip_runtime.h>
#include <math.h>

#define T_STEPS 8192
#define I_DIM   64
#define H_DIM   2048
#define O_DIM   128
#define NBLK    256     // one block per CU; each owns 8 h-indices (32 gate rows)
#define NTHR    512     // 8 waves
#define NSLOT   4       // h slot ring depth
#define REPL    8       // one h replica per XCD
#define SLOT_W  (REPL * H_DIM)   // 16384 words per slot (8 replicas x 8KB)
#define NAN_BITS 0x7FC00000u

typedef float v4f __attribute__((ext_vector_type(4)));

// ws layout: uint Hbits[NSLOT][REPL][2048] (256 KB). Replica r of a slot is a
// full h image consumed ONLY by CUs on XCD r (probe fan-out 1 per line) —
// round-5 proven, -4.5%.
__device__ __forceinline__ float sigmoid_f(float x) {
    return 1.0f / (1.0f + __expf(-x));
}
__device__ __forceinline__ float tanh_fast(float x) {
    // 2*sigmoid(2x)-1; saturates correctly for |x| large
    return 2.0f / (1.0f + __expf(-2.0f * x)) - 1.0f;
}

// DPP-based wave64 sum — VALU pipe, NOT the LDS pipe. CTRL must be immediate.
template <int CTRL>
__device__ __forceinline__ float dpp_add(float v) {
    int s = __builtin_amdgcn_update_dpp(0, __builtin_bit_cast(int, v),
                                        CTRL, 0xF, 0xF, true);
    return v + __builtin_bit_cast(float, s);
}
// After the sequence, lane 63 holds the full 64-lane sum.
__device__ __forceinline__ float wave_sum64_lane63(float v) {
    v = dpp_add<0x111>(v);  // row_shr:1
    v = dpp_add<0x112>(v);  // row_shr:2
    v = dpp_add<0x114>(v);  // row_shr:4
    v = dpp_add<0x118>(v);  // row_shr:8   -> lane15 of each row16 = row-partial
    v = dpp_add<0x142>(v);  // row_bcast:15 -> lane31 = sum(0..31), l63 = sum(32..63)
    v = dpp_add<0x143>(v);  // row_bcast:31 -> lane63 = sum(0..63)
    return v;
}

__global__ void init_ws_kernel(unsigned int* Hbits) {
    int tid = blockIdx.x * blockDim.x + threadIdx.x;
    if (tid < NSLOT * SLOT_W) {
        // slot 0 (all 8 replicas) = h_0 = 0.0f; slots 1..3 = NaN sentinel
        Hbits[tid] = (tid < SLOT_W) ? 0u : NAN_BITS;
    }
}

// Persistent LSTM recurrence — round-5 fabric (17.63 ms: replicas + sleep(1))
// with ONE structural change on the publisher-side tail: gate-complete wave
// decomposition. Wave w owns h-index hj=cu*8+w and computes its 4 gate rows
// {g*2048+hj}; the DPP reduce lands i/f/g/o in lane 63 of the SAME wave ->
// elementwise + cstate in lane 63, NO gbuf, NO barrier #2 (removes a barrier
// + an LDS round-trip from the publish critical path). Publish: lane63 drops
// h into an 8-word NaN-flag LDS buffer; wave 0 spins (short; waves finish
// reduce+ew ~simultaneously) and issues the IDENTICAL one-instruction 64-lane
// replica store (lane l -> replica l>>3, word cu*8+(l&7)).
// hbuf/xbuf are parity double-buffered: a thread stages step t+1 only after
// poll(t+1) success; all waves passed barrier1(t+1) only after finishing
// dot(t) (program order), so writes to parity p at t+2 cannot overlap reads
// of parity p at t — the round-1 correctness argument (which PASSED; its
// slowness was the poll surgery, NOT this decomposition; poll kept verbatim).
// Deviation ledger (all measured worse): hot-spin/predicated poll +20% and
// collapse; hand-asm sc1 16B poll +16%; 64B per-CU line padding +41%.
// Proven: sleep(2)->(1) -3.7%; XCD replicas -4.5%.
// Dot k-mapping: lane l covers k = m*256 + l*4 + j -> one ds_read_b128 per m.
__global__ __launch_bounds__(NTHR, 2) void lstm_persistent(
    const float* __restrict__ x,     // [T, 64]
    const float* __restrict__ Wih,   // [8192, 64]
    const float* __restrict__ Whh,   // [8192, 2048]
    const float* __restrict__ bih,   // [8192]
    const float* __restrict__ bhh,   // [8192]
    unsigned int* __restrict__ Hbits)// [NSLOT][REPL][2048] in ws (float bits)
{
    const int cu   = blockIdx.x;
    const int tid  = threadIdx.x;
    const int w    = tid >> 6;
    const int lane = tid & 63;
    const int hj   = cu * 8 + w;     // this wave's h-index

    __shared__ float        hbuf[2][H_DIM];   // 16 KB, parity double-buffer
    __shared__ float        xbuf[2][I_DIM];
    __shared__ unsigned int houtb[8];         // per-step h gather, NaN-flagged

    // which XCD am I on? (stable for a persistent block; locality-only —
    // ANY value 0..7 is correct since all replicas are written)
    unsigned int xcc;
    asm volatile("s_getreg_b32 %0, hwreg(HW_REG_XCC_ID)" : "=s"(xcc));
    const int myrep = (int)(xcc & 7u);

    // ---- one-time: W_hh fragment into registers (unified VGPR/AGPR file) ----
    // wreg[g][m] = Whh[g*2048+hj][m*256 + lane*4 .. +3]   (coalesced 16B loads)
    v4f wreg[4][8];
#pragma unroll
    for (int g = 0; g < 4; g++) {
        const float* p = Whh + (size_t)(g * H_DIM + hj) * H_DIM + lane * 4;
#pragma unroll
        for (int m = 0; m < 8; m++)
            wreg[g][m] = *(const v4f*)(p + m * 256);
    }
    // x-part: lane covers gate (lane>>4) of row hj, k-range (lane&15)*4 .. +4
    float xw[4];
    {
        const int xr = (lane >> 4) * H_DIM + hj;
        const float* p = Wih + (size_t)xr * I_DIM + (lane & 15) * 4;
#pragma unroll
        for (int m = 0; m < 4; m++) xw[m] = p[m];
    }
    // biases for h-index hj (uniform across the wave; used by lane 63)
    float bias[4];
#pragma unroll
    for (int g = 0; g < 4; g++) {
        int r = g * H_DIM + hj;
        bias[g] = bih[r] + bhh[r];
    }
    float cstate = 0.0f;   // meaningful in lane 63 of each wave

    if (tid < 8) houtb[tid] = NAN_BITS;
    __syncthreads();

    for (int t = 0; t < T_STEPS; t++) {
        const int par    = t & 1;
        const int slot_r = t & (NSLOT - 1);
        const int slot_w = (t + 1) & (NSLOT - 1);
        const int slot_z = (t + 2) & (NSLOT - 1);

        // hoist the independent x load above the spin
        float xv_own = (tid < I_DIM) ? x[(size_t)t * I_DIM + tid] : 0.0f;

        // ---- 1. poll h_t from MY XCD's replica (data-as-flag), stage to LDS ----
        // 4x 4B compiler-emitted atomic loads, batch reload, s_sleep(1) on
        // EVERY failed pass — round-5 proven verbatim (do not hand-roll; do
        // not predicate; do not hot-spin).
        {
            const unsigned int* Hr = Hbits + slot_r * SLOT_W + myrep * H_DIM;
            unsigned int u0, u1, u2, u3;
            for (;;) {
                u0 = __hip_atomic_load(Hr + tid,             __ATOMIC_RELAXED, __HIP_MEMORY_SCOPE_AGENT);
                u1 = __hip_atomic_load(Hr + tid + 1 * NTHR,  __ATOMIC_RELAXED, __HIP_MEMORY_SCOPE_AGENT);
                u2 = __hip_atomic_load(Hr + tid + 2 * NTHR,  __ATOMIC_RELAXED, __HIP_MEMORY_SCOPE_AGENT);
                u3 = __hip_atomic_load(Hr + tid + 3 * NTHR,  __ATOMIC_RELAXED, __HIP_MEMORY_SCOPE_AGENT);
                bool miss = (u0 == NAN_BITS) | (u1 == NAN_BITS) |
                            (u2 == NAN_BITS) | (u3 == NAN_BITS);
                if (!miss) break;
                __builtin_amdgcn_s_sleep(1);
            }
            hbuf[par][tid]            = __uint_as_float(u0);
            hbuf[par][tid + 1 * NTHR] = __uint_as_float(u1);
            hbuf[par][tid + 2 * NTHR] = __uint_as_float(u2);
            hbuf[par][tid + 3 * NTHR] = __uint_as_float(u3);
            if (tid < I_DIM) xbuf[par][tid] = xv_own;
        }
        // reset own chunk in ALL replicas 2 slots ahead (holds h_{t-2}, fully
        // consumed; ring-safety: poll success at t implies no CU still reads
        // slot (t+2)&3). One 64-lane store, 8x32B transactions.
        if (w == 0) {
            __hip_atomic_store(Hbits + slot_z * SLOT_W + (lane >> 3) * H_DIM
                                   + cu * 8 + (lane & 7), NAN_BITS,
                               __ATOMIC_RELAXED, __HIP_MEMORY_SCOPE_AGENT);
        }
        __syncthreads();   // the ONLY barrier per step

        // ---- 2. dot: 4 gate rows of h-index hj, 8 x (ds_read_b128 + v4f FMA) ----
        v4f av0 = {0.f,0.f,0.f,0.f}, av1 = {0.f,0.f,0.f,0.f};
        v4f av2 = {0.f,0.f,0.f,0.f}, av3 = {0.f,0.f,0.f,0.f};
#pragma unroll
        for (int m = 0; m < 8; m++) {
            v4f hv = *(const v4f*)&hbuf[par][m * 256 + lane * 4];
            av0 += wreg[0][m] * hv;
            av1 += wreg[1][m] * hv;
            av2 += wreg[2][m] * hv;
            av3 += wreg[3][m] * hv;
        }
        float acc0 = (av0[0] + av0[1]) + (av0[2] + av0[3]);
        float acc1 = (av1[0] + av1[1]) + (av1[2] + av1[3]);
        float acc2 = (av2[0] + av2[1]) + (av2[2] + av2[3]);
        float acc3 = (av3[0] + av3[1]) + (av3[2] + av3[3]);
        {   // fold in W_ih * x_t : lane's xp belongs to gate sel=lane>>4
            float xp = 0.f;
            const int b = (lane & 15) * 4;
#pragma unroll
            for (int m = 0; m < 4; m++) xp += xw[m] * xbuf[par][b + m];
            const int sel = lane >> 4;
            acc0 += (sel == 0) ? xp : 0.0f;
            acc1 += (sel == 1) ? xp : 0.0f;
            acc2 += (sel == 2) ? xp : 0.0f;
            acc3 += (sel == 3) ? xp : 0.0f;
        }
        // ---- 3. DPP reduction; all four gates land in lane 63 of this wave ----
        acc0 = wave_sum64_lane63(acc0);
        acc1 = wave_sum64_lane63(acc1);
        acc2 = wave_sum64_lane63(acc2);
        acc3 = wave_sum64_lane63(acc3);

        // ---- 4. elementwise in lane 63; hand h to wave 0 via NaN-flag LDS ----
        if (lane == 63) {
            float iv = sigmoid_f(acc0 + bias[0]);
            float fv = sigmoid_f(acc1 + bias[1]);
            float gv = tanh_fast(acc2 + bias[2]);
            float ov = sigmoid_f(acc3 + bias[3]);
            cstate = fv * cstate + iv * gv;
            float hval = ov * tanh_fast(cstate);
            __hip_atomic_store(&houtb[w], __float_as_uint(hval),
                               __ATOMIC_RELAXED, __HIP_MEMORY_SCOPE_WORKGROUP);
        }
        // ---- 5. wave 0 gathers 8 values (short LDS spin; waves finish
        //         reduce+ew ~simultaneously) and publishes ALL 8 replicas
        //         with ONE 64-lane store — identical shape to round 5 ----
        if (w == 0) {
            unsigned int hb;
            do {
                hb = __hip_atomic_load(&houtb[lane & 7],
                                       __ATOMIC_RELAXED, __HIP_MEMORY_SCOPE_WORKGROUP);
            } while (hb == NAN_BITS);
            __hip_atomic_store(Hbits + slot_w * SLOT_W + (lane >> 3) * H_DIM
                                   + cu * 8 + (lane & 7), hb,
                               __ATOMIC_RELAXED, __HIP_MEMORY_SCOPE_AGENT);
            // re-arm flags for the next step. Safe: the next lane63 write to
            // houtb happens only after barrier1(t+1), which wave 0 reaches
            // after this reset (program order) — no race.
            if (lane < 8) {
                __hip_atomic_store(&houtb[lane], NAN_BITS,
                                   __ATOMIC_RELAXED, __HIP_MEMORY_SCOPE_WORKGROUP);
            }
        }
        // other waves run straight into step t+1's poll (early start; their
        // own-CU chunk arrives only after wave 0's publish anyway).
    }
}

// Final linear: out[o] = h_T . W_lin[o,:] + b_lin[o].  One wave per output.
// h_T lives in slot (T & 3) == 0, replica 0 (== base of Hbits).
__global__ void final_linear(const float* __restrict__ hT,
                             const float* __restrict__ Wlin,
                             const float* __restrict__ blin,
                             float* __restrict__ out)
{
    int gw   = (blockIdx.x * blockDim.x + threadIdx.x) >> 6;
    int lane = threadIdx.x & 63;
    if (gw < O_DIM) {
        const float* wp = Wlin + (size_t)gw * H_DIM;
        float s = 0.f;
        for (int k = lane; k < H_DIM; k += 64)
            s += wp[k] * hT[k];
#pragma unroll
        for (int off = 32; off; off >>= 1) s += __shfl_xor(s, off, 64);
        if (lane == 0) out[gw] = s + blin[gw];
    }
}

extern "C" void kernel_launch(void* const* d_in, const int* in_sizes, int n_in,
                              void* d_out, int out_size, void* d_ws, size_t ws_size,
                              hipStream_t stream)
{
    const float* x    = (const float*)d_in[0];
    const float* Wih  = (const float*)d_in[1];
    const float* Whh  = (const float*)d_in[2];
    const float* bih  = (const float*)d_in[3];
    const float* bhh  = (const float*)d_in[4];
    const float* Wlin = (const float*)d_in[5];
    const float* blin = (const float*)d_in[6];
    float* out = (float*)d_out;

    unsigned int* Hbits = (unsigned int*)d_ws;

    hipLaunchKernelGGL(init_ws_kernel, dim3((NSLOT * SLOT_W + 255) / 256), dim3(256),
                       0, stream, Hbits);

    void* args[] = { (void*)&x, (void*)&Wih, (void*)&Whh, (void*)&bih, (void*)&bhh,
                     (void*)&Hbits };
    (void)hipLaunchCooperativeKernel(reinterpret_cast<void*>(lstm_persistent),
                                     dim3(NBLK), dim3(NTHR), args, 0, stream);

    // h_T is in slot (T_STEPS & 3) == 0, replica 0
    hipLaunchKernelGGL(final_linear, dim3(32), dim3(256), 0, stream,
                       (const float*)Hbits, Wlin, blin, out);
}

// Round 7
// 17635.529 us; speedup vs baseline: 1.0487x; 1.0487x over previous
//
#include <hip/hip_runtime.h>
#include <math.h>

#define T_STEPS 8192
#define I_DIM   64
#define H_DIM   2048
#define O_DIM   128
#define NBLK    256     // one block per CU; each owns 8 h-indices (32 gate rows)
#define NTHR    512     // 8 waves
#define NSLOT   4       // h slot ring depth
#define REPL    8       // one h replica per XCD
#define SLOT_W  (REPL * H_DIM)   // 16384 words per slot (8 replicas x 8KB)
#define NAN_BITS 0x7FC00000u

typedef float v4f __attribute__((ext_vector_type(4)));

// ws layout: uint Hbits[NSLOT][REPL][2048] (256 KB). Replica r of a slot is a
// full h image consumed ONLY by CUs on XCD r -> every 64B line has exactly one
// publisher and one consumer-XCD: probe fan-out 1, no 8-XCD concurrent refetch
// of the same hot line.
__device__ __forceinline__ float sigmoid_f(float x) {
    return 1.0f / (1.0f + __expf(-x));
}
__device__ __forceinline__ float tanh_fast(float x) {
    // 2*sigmoid(2x)-1; saturates correctly for |x| large
    return 2.0f / (1.0f + __expf(-2.0f * x)) - 1.0f;
}

// DPP-based wave64 sum — VALU pipe, NOT the LDS pipe. CTRL must be immediate.
template <int CTRL>
__device__ __forceinline__ float dpp_add(float v) {
    int s = __builtin_amdgcn_update_dpp(0, __builtin_bit_cast(int, v),
                                        CTRL, 0xF, 0xF, true);
    return v + __builtin_bit_cast(float, s);
}
// After the sequence, lane 63 holds the full 64-lane sum.
__device__ __forceinline__ float wave_sum64_lane63(float v) {
    v = dpp_add<0x111>(v);  // row_shr:1
    v = dpp_add<0x112>(v);  // row_shr:2
    v = dpp_add<0x114>(v);  // row_shr:4
    v = dpp_add<0x118>(v);  // row_shr:8   -> lane15 of each row16 = row-partial
    v = dpp_add<0x142>(v);  // row_bcast:15 -> lane31 = sum(0..31), l63 = sum(32..63)
    v = dpp_add<0x143>(v);  // row_bcast:31 -> lane63 = sum(0..63)
    return v;
}

__global__ void init_ws_kernel(unsigned int* Hbits) {
    int tid = blockIdx.x * blockDim.x + threadIdx.x;
    if (tid < NSLOT * SLOT_W) {
        // slot 0 (all 8 replicas) = h_0 = 0.0f; slots 1..3 = NaN sentinel
        Hbits[tid] = (tid < SLOT_W) ? 0u : NAN_BITS;
    }
}

// Persistent LSTM recurrence — FINAL form (round-5, 17.63 ms): round-0 fabric
// + sleep(1) (r4, -3.7%) + XCD-local replica publish/poll (r5, -4.5%).
//  publish: wave 0, all 64 lanes, ONE store instruction; lane l -> replica
//           (l>>3), word cu*8+(l&7).
//  poll:    each CU polls replica XCC_ID&7 (s_getreg, HW-verified). Value is
//           locality-only — ANY 0..7 is correct since all replicas are written.
// Deviation ledger (all measured worse; do not retry): hot-spin/predicated
// poll +20% & collapse (r1); hand-asm sc1 16B poll +16% (r2); 64B per-CU line
// padding +41% (r3); gate-complete 1-barrier LDS-gather publish +4.9% (r6).
// Wave w: gate q = w>>1, joff = (w&1)*4; rows = q*2048 + cu*8 + joff + i
// Dot k-mapping: lane l covers k = m*256 + l*4 + j -> one ds_read_b128 per m.
__global__ __launch_bounds__(NTHR, 2) void lstm_persistent(
    const float* __restrict__ x,     // [T, 64]
    const float* __restrict__ Wih,   // [8192, 64]
    const float* __restrict__ Whh,   // [8192, 2048]
    const float* __restrict__ bih,   // [8192]
    const float* __restrict__ bhh,   // [8192]
    unsigned int* __restrict__ Hbits)// [NSLOT][REPL][2048] in ws (float bits)
{
    const int cu   = blockIdx.x;
    const int tid  = threadIdx.x;
    const int w    = tid >> 6;
    const int lane = tid & 63;

    __shared__ float hbuf[H_DIM];   // 8 KB, layout hbuf[k] = h[k]
    __shared__ float xbuf[I_DIM];
    __shared__ float gbuf[32];      // gbuf[g*8 + j] = pre-activation of gate g, h-sub j

    const int q    = w >> 1;
    const int joff = (w & 1) * 4;
    const int row0 = q * H_DIM + cu * 8 + joff;

    // which XCD am I on? (stable for a persistent block; locality-only)
    unsigned int xcc;
    asm volatile("s_getreg_b32 %0, hwreg(HW_REG_XCC_ID)" : "=s"(xcc));
    const int myrep = (int)(xcc & 7u);

    // ---- one-time: W_hh fragment into registers (unified VGPR/AGPR file) ----
    // wreg[i][m] = W[row0+i][m*256 + lane*4 .. +3]   (coalesced 16B loads)
    v4f wreg[4][8];
#pragma unroll
    for (int i = 0; i < 4; i++) {
        const float* p = Whh + (size_t)(row0 + i) * H_DIM + lane * 4;
#pragma unroll
        for (int m = 0; m < 8; m++)
            wreg[i][m] = *(const v4f*)(p + m * 256);
    }
    // x-part: lane handles row (row0 + (lane>>4)), k-range (lane&15)*4 .. +4
    float xw[4];
    {
        const int xr = row0 + (lane >> 4);
        const float* p = Wih + (size_t)xr * I_DIM + (lane & 15) * 4;
#pragma unroll
        for (int m = 0; m < 4; m++) xw[m] = p[m];
    }
    // biases: ALL lanes keep them for h-index (lane&7) — elementwise phase is
    // replicated per 8-lane group so wave 0's 64 lanes can publish 8 replicas.
    float bias[4];
#pragma unroll
    for (int g = 0; g < 4; g++) {
        int r = g * H_DIM + cu * 8 + (lane & 7);
        bias[g] = bih[r] + bhh[r];
    }
    float cstate = 0.0f;   // replicated: each lane tracks c for h-index (lane&7)

    for (int t = 0; t < T_STEPS; t++) {
        const int slot_r = t & (NSLOT - 1);
        const int slot_w = (t + 1) & (NSLOT - 1);
        const int slot_z = (t + 2) & (NSLOT - 1);

        // hoist the independent x load above the spin
        float xv_own = (tid < I_DIM) ? x[(size_t)t * I_DIM + tid] : 0.0f;

        // ---- 1. poll h_t from MY XCD's replica (data-as-flag), stage to LDS ----
        // 4x 4B compiler-emitted atomic loads (do not hand-roll — round 2);
        // s_sleep(1) on EVERY failed pass (round-4 proven cadence).
        {
            const unsigned int* Hr = Hbits + slot_r * SLOT_W + myrep * H_DIM;
            unsigned int u0, u1, u2, u3;
            for (;;) {
                u0 = __hip_atomic_load(Hr + tid,             __ATOMIC_RELAXED, __HIP_MEMORY_SCOPE_AGENT);
                u1 = __hip_atomic_load(Hr + tid + 1 * NTHR,  __ATOMIC_RELAXED, __HIP_MEMORY_SCOPE_AGENT);
                u2 = __hip_atomic_load(Hr + tid + 2 * NTHR,  __ATOMIC_RELAXED, __HIP_MEMORY_SCOPE_AGENT);
                u3 = __hip_atomic_load(Hr + tid + 3 * NTHR,  __ATOMIC_RELAXED, __HIP_MEMORY_SCOPE_AGENT);
                bool miss = (u0 == NAN_BITS) | (u1 == NAN_BITS) |
                            (u2 == NAN_BITS) | (u3 == NAN_BITS);
                if (!miss) break;
                __builtin_amdgcn_s_sleep(1);
            }
            hbuf[tid]            = __uint_as_float(u0);
            hbuf[tid + 1 * NTHR] = __uint_as_float(u1);
            hbuf[tid + 2 * NTHR] = __uint_as_float(u2);
            hbuf[tid + 3 * NTHR] = __uint_as_float(u3);
            if (tid < I_DIM) xbuf[tid] = xv_own;
        }
        // reset own chunk in ALL replicas 2 slots ahead (holds h_{t-2}, fully
        // consumed; ring-safety unchanged — poll success at t implies no CU is
        // still reading slot (t+2)&3). One 64-lane store, 8x32B transactions.
        if (w == 0) {
            __hip_atomic_store(Hbits + slot_z * SLOT_W + (lane >> 3) * H_DIM
                                   + cu * 8 + (lane & 7), NAN_BITS,
                               __ATOMIC_RELAXED, __HIP_MEMORY_SCOPE_AGENT);
        }
        __syncthreads();

        // ---- 2. dot products: 4 rows per wave, 8 x (ds_read_b128 + packed FMA) ----
        v4f av0 = {0.f,0.f,0.f,0.f}, av1 = {0.f,0.f,0.f,0.f};
        v4f av2 = {0.f,0.f,0.f,0.f}, av3 = {0.f,0.f,0.f,0.f};
#pragma unroll
        for (int m = 0; m < 8; m++) {
            v4f hv = *(const v4f*)&hbuf[m * 256 + lane * 4];
            av0 += wreg[0][m] * hv;
            av1 += wreg[1][m] * hv;
            av2 += wreg[2][m] * hv;
            av3 += wreg[3][m] * hv;
        }
        float acc0 = (av0[0] + av0[1]) + (av0[2] + av0[3]);
        float acc1 = (av1[0] + av1[1]) + (av1[2] + av1[3]);
        float acc2 = (av2[0] + av2[1]) + (av2[2] + av2[3]);
        float acc3 = (av3[0] + av3[1]) + (av3[2] + av3[3]);
        {   // fold in W_ih * x_t
            float xp = 0.f;
            const int b = (lane & 15) * 4;
#pragma unroll
            for (int m = 0; m < 4; m++) xp += xw[m] * xbuf[b + m];
            const int sel = lane >> 4;
            acc0 += (sel == 0) ? xp : 0.0f;
            acc1 += (sel == 1) ? xp : 0.0f;
            acc2 += (sel == 2) ? xp : 0.0f;
            acc3 += (sel == 3) ? xp : 0.0f;
        }
        // ---- 3. DPP reduction (VALU pipe); totals land in lane 63 ----
        acc0 = wave_sum64_lane63(acc0);
        acc1 = wave_sum64_lane63(acc1);
        acc2 = wave_sum64_lane63(acc2);
        acc3 = wave_sum64_lane63(acc3);
        if (lane == 63) {
            gbuf[q * 8 + joff + 0] = acc0;
            gbuf[q * 8 + joff + 1] = acc1;
            gbuf[q * 8 + joff + 2] = acc2;
            gbuf[q * 8 + joff + 3] = acc3;
        }
        __syncthreads();

        // ---- 4. elementwise cell update, replicated per 8-lane group (all
        //         waves, for cstate continuity); wave 0 publishes ALL 8
        //         replicas with ONE 64-lane store instruction ----
        {
            const int j = lane & 7;
            float gi = gbuf[0 * 8 + j] + bias[0];
            float gf = gbuf[1 * 8 + j] + bias[1];
            float gg = gbuf[2 * 8 + j] + bias[2];
            float go = gbuf[3 * 8 + j] + bias[3];
            float iv = sigmoid_f(gi);
            float fv = sigmoid_f(gf);
            float gv = tanh_fast(gg);
            float ov = sigmoid_f(go);
            cstate = fv * cstate + iv * gv;
            float hval = ov * tanh_fast(cstate);
            if (w == 0) {
                __hip_atomic_store(Hbits + slot_w * SLOT_W + (lane >> 3) * H_DIM
                                       + cu * 8 + j,
                                   __float_as_uint(hval),
                                   __ATOMIC_RELAXED, __HIP_MEMORY_SCOPE_AGENT);
            }
        }
        // next iteration's poll phase touches only Hbits/hbuf/xbuf; gbuf reuse
        // is protected by the next iteration's first __syncthreads.
    }
}

// Final linear: out[o] = h_T . W_lin[o,:] + b_lin[o].  One wave per output.
// h_T lives in slot (T & 3) == 0, replica 0 (== base of Hbits).
__global__ void final_linear(const float* __restrict__ hT,
                             const float* __restrict__ Wlin,
                             const float* __restrict__ blin,
                             float* __restrict__ out)
{
    int gw   = (blockIdx.x * blockDim.x + threadIdx.x) >> 6;
    int lane = threadIdx.x & 63;
    if (gw < O_DIM) {
        const float* wp = Wlin + (size_t)gw * H_DIM;
        float s = 0.f;
        for (int k = lane; k < H_DIM; k += 64)
            s += wp[k] * hT[k];
#pragma unroll
        for (int off = 32; off; off >>= 1) s += __shfl_xor(s, off, 64);
        if (lane == 0) out[gw] = s + blin[gw];
    }
}

extern "C" void kernel_launch(void* const* d_in, const int* in_sizes, int n_in,
                              void* d_out, int out_size, void* d_ws, size_t ws_size,
                              hipStream_t stream)
{
    const float* x    = (const float*)d_in[0];
    const float* Wih  = (const float*)d_in[1];
    const float* Whh  = (const float*)d_in[2];
    const float* bih  = (const float*)d_in[3];
    const float* bhh  = (const float*)d_in[4];
    const float* Wlin = (const float*)d_in[5];
    const float* blin = (const float*)d_in[6];
    float* out = (float*)d_out;

    unsigned int* Hbits = (unsigned int*)d_ws;

    hipLaunchKernelGGL(init_ws_kernel, dim3((NSLOT * SLOT_W + 255) / 256), dim3(256),
                       0, stream, Hbits);

    void* args[] = { (void*)&x, (void*)&Wih, (void*)&Whh, (void*)&bih, (void*)&bhh,
                     (void*)&Hbits };
    (void)hipLaunchCooperativeKernel(reinterpret_cast<void*>(lstm_persistent),
                                     dim3(NBLK), dim3(NTHR), args, 0, stream);

    // h_T is in slot (T_STEPS & 3) == 0, replica 0
    hipLaunchKernelGGL(final_linear, dim3(32), dim3(256), 0, stream,
                       (const float*)Hbits, Wlin, blin, out);
}